// Round 4
// baseline (247.027 us; speedup 1.0000x reference)
//
#include <hip/hip_runtime.h>
#include <hip/hip_bf16.h>

// GeometricAttention on MI355X (gfx950).
// B=2, T=2048, C=1024, H=16, hd=64, QK-dim=3.
// HARNESS DTYPES: reference is pure float32 -> d_in are float*, d_out is float*.
// Internally bf16 for MFMA (fp32 accumulate); scores in fp32.
// R4: barrier-free k_attn (P built in A-frag layout, K/V read from global,
//     rowsum via ones-B-frag); gemm 64x128 tiles (512 blocks); qkproj split-K x4.

typedef short bf16x8 __attribute__((ext_vector_type(8)));
typedef float f32x4 __attribute__((ext_vector_type(4)));
typedef __hip_bfloat16 bf16_t;
typedef unsigned int __attribute__((address_space(1))) u32_as1;
typedef unsigned int __attribute__((address_space(3))) u32_as3;

#define T_SEQ 2048
#define NHEAD 16
#define CDIM 1024

__device__ __forceinline__ void gl_lds16(const void* g, void* l) {
  __builtin_amdgcn_global_load_lds((const u32_as1*)g, (u32_as3*)l, 16, 0, 0);
}

__device__ __forceinline__ f32x4 mfma16(bf16x8 a, bf16x8 b, f32x4 c) {
  return __builtin_amdgcn_mfma_f32_16x16x32_bf16(a, b, c, 0, 0, 0);
}

__device__ __forceinline__ unsigned short f2bf(float f) {
  __hip_bfloat16 h = __float2bfloat16(f);
  return *(unsigned short*)&h;
}

// ---------------- cast fp32 -> bf16, 4 elems/thread ----------------
__global__ __launch_bounds__(256) void k_cast(const float4* __restrict__ src,
                                              ushort4* __restrict__ dst, int n4) {
  int i = blockIdx.x * 256 + threadIdx.x;
  if (i < n4) {
    float4 v = src[i];
    ushort4 o;
    o.x = f2bf(v.x); o.y = f2bf(v.y); o.z = f2bf(v.z); o.w = f2bf(v.w);
    dst[i] = o;
  }
}

// ---------------- transpose+cast (fp32 R x C -> bf16 C x R) ----------------
__global__ __launch_bounds__(256) void k_transpose(const float* __restrict__ src,
                                                   bf16_t* __restrict__ dst,
                                                   int R, int C) {
  __shared__ bf16_t tile[32][33];
  int tid = threadIdx.x, tx = tid & 31, ty = tid >> 5;
  int r0 = blockIdx.y * 32, c0 = blockIdx.x * 32;
#pragma unroll
  for (int j = 0; j < 32; j += 8) {
    int r = r0 + ty + j, c = c0 + tx;
    if (r < R && c < C) tile[ty + j][tx] = __float2bfloat16(src[(size_t)r * C + c]);
  }
  __syncthreads();
#pragma unroll
  for (int j = 0; j < 32; j += 8) {
    int c = c0 + ty + j, r = r0 + tx;
    if (r < R && c < C) dst[(size_t)c * R + r] = tile[tx][ty + j];
  }
}

// ---------------- QK projection (M=4096, N=96, K=1024), split-K x4 ----------------
// block: 16 rows, 4 waves each own a K-quarter; LDS reduce; then Q transform.
__global__ __launch_bounds__(256) void k_qkproj(const bf16_t* __restrict__ xb,
                                                const bf16_t* __restrict__ wqkT,
                                                const float* __restrict__ head_dirs,
                                                const float* __restrict__ scale,
                                                float* __restrict__ Qt,
                                                float* __restrict__ Kt) {
  __shared__ float red[4][16][96];  // 24 KB
  int tid = threadIdx.x, wave = tid >> 6, lane = tid & 63;
  int g = lane >> 4, li = lane & 15;
  int m0 = blockIdx.x * 16;
  f32x4 acc[6] = {};
  int kb = wave * 256;
  for (int k0 = kb; k0 < kb + 256; k0 += 32) {
    bf16x8 a = *(const bf16x8*)(xb + (size_t)(m0 + li) * 1024 + k0 + g * 8);
#pragma unroll
    for (int nt = 0; nt < 6; ++nt) {
      bf16x8 bb = *(const bf16x8*)(wqkT + (size_t)(nt * 16 + li) * 1024 + k0 + g * 8);
      acc[nt] = mfma16(a, bb, acc[nt]);
    }
  }
#pragma unroll
  for (int nt = 0; nt < 6; ++nt)
#pragma unroll
    for (int r = 0; r < 4; ++r) red[wave][g * 4 + r][nt * 16 + li] = acc[nt][r];
  __syncthreads();
  // reduce 4 partials; K cols -> Kt, Q cols -> red[0]
  for (int i = tid; i < 16 * 96; i += 256) {
    int row = i / 96, col = i - (i / 96) * 96;
    float v = red[0][row][col] + red[1][row][col] + red[2][row][col] + red[3][row][col];
    if (col >= 48) {
      int n = col - 48;          // 0..47
      int h = n / 3, c = n - h * 3;
      int mg = m0 + row;
      int bb = mg >> 11, tt = mg & 2047;
      Kt[(((size_t)bb * NHEAD + h) * 3 + c) * T_SEQ + tt] = v;
    } else {
      red[0][row][col] = v;
    }
  }
  __syncthreads();
  // Q transform: 256 threads = 16 rows x 16 heads
  int row = tid >> 4, h = tid & 15;
  float q0 = red[0][row][h * 3 + 0];
  float q1 = red[0][row][h * 3 + 1];
  float q2 = red[0][row][h * 3 + 2];
  float d0 = head_dirs[h * 3 + 0];
  float d1 = head_dirs[h * 3 + 1];
  float d2 = head_dirs[h * 3 + 2];
  float sc = scale[0];
  float dot = q0 * d0 + q1 * d1 + q2 * d2;
  int mg = m0 + row;
  int bb = mg >> 11, tt = mg & 2047;
  size_t base = ((size_t)bb * NHEAD + h) * 3 * T_SEQ + tt;
  Qt[base] = sc * q0 + d0 * dot;
  Qt[base + T_SEQ] = sc * q1 + d1 * dot;
  Qt[base + 2 * T_SEQ] = sc * q2 + d2 * dot;
}

// ---------------- 64x128x32 MFMA GEMM, B^T input ----------------
// C[m][n] = sum_k A[m][k] * Bt[n][k]; 512 blocks -> 2 blocks/CU overlap.
// mode 0: bf16 out, VT planes: n=(b,t), store at [(b*1024+m)*2048 + t]
// mode 1: fp32 out, row-major m*N+n
__global__ __launch_bounds__(256) void k_gemm_bt(const bf16_t* __restrict__ A,
                                                 const bf16_t* __restrict__ Bt,
                                                 void* __restrict__ Cout,
                                                 int M, int N, int K, int mode) {
  __shared__ alignas(16) bf16_t As[64 * 32];
  __shared__ alignas(16) bf16_t Bs[128 * 32];
  int tid = threadIdx.x, wave = tid >> 6, lane = tid & 63;
  int g = lane >> 4, li = lane & 15;
  int n0 = blockIdx.x * 128, m0 = blockIdx.y * 64;
  int wm = wave >> 1, wn = wave & 1;

  const bf16_t* gA0 = A + (size_t)(m0 + (tid >> 2)) * K + (tid & 3) * 8;
  const bf16_t* gB0 = Bt + (size_t)(n0 + (tid >> 2)) * K + (tid & 3) * 8;
  const bf16_t* gB1 = Bt + (size_t)(n0 + 64 + (tid >> 2)) * K + (tid & 3) * 8;
  char* lA = (char*)As + (size_t)(wave * 64) * 16;          // + lane*16 implicit
  char* lB0 = (char*)Bs + (size_t)(wave * 64) * 16;
  char* lB1 = (char*)Bs + (size_t)(256 + wave * 64) * 16;

  f32x4 acc[2][4] = {};

  for (int k0 = 0; k0 < K; k0 += 32) {
    __syncthreads();
    gl_lds16(gA0 + k0, lA);
    gl_lds16(gB0 + k0, lB0);
    gl_lds16(gB1 + k0, lB1);
    __syncthreads();
    bf16x8 af[2], bfr[4];
#pragma unroll
    for (int mt = 0; mt < 2; ++mt)
      af[mt] = *(const bf16x8*)&As[(wm * 32 + mt * 16 + li) * 32 + g * 8];
#pragma unroll
    for (int nt = 0; nt < 4; ++nt)
      bfr[nt] = *(const bf16x8*)&Bs[(wn * 64 + nt * 16 + li) * 32 + g * 8];
#pragma unroll
    for (int mt = 0; mt < 2; ++mt)
#pragma unroll
      for (int nt = 0; nt < 4; ++nt)
        acc[mt][nt] = mfma16(af[mt], bfr[nt], acc[mt][nt]);
  }

#pragma unroll
  for (int mt = 0; mt < 2; ++mt)
#pragma unroll
    for (int nt = 0; nt < 4; ++nt)
#pragma unroll
      for (int r = 0; r < 4; ++r) {
        int m = m0 + wm * 32 + mt * 16 + g * 4 + r;
        int n = n0 + wn * 64 + nt * 16 + li;
        float v = acc[mt][nt][r];
        if (mode == 0) {
          int bb = n >> 11, tt = n & 2047;
          ((bf16_t*)Cout)[((size_t)bb * 1024 + m) * T_SEQ + tt] = __float2bfloat16(v);
        } else {
          ((float*)Cout)[(size_t)m * N + n] = v;
        }
      }
}

// ---------------- attention (barrier-free, no LDS) ----------------
// block = 256 thr (4 waves), one (b,h) x 64-query tile; wave = 16 queries.
// P built directly in A-frag layout: lane li = query mw+li, k-slot g*8+j = key.
// K read from global (group-uniform -> broadcast, L1-hot); V B-frags from global
// (L2-hot). Rowsums via constant ones B-frag (D[:,0] = row sums).
__global__ __launch_bounds__(256) void k_attn(const float* __restrict__ Qt,
                                              const float* __restrict__ Kt,
                                              const bf16_t* __restrict__ VT,
                                              bf16_t* __restrict__ att) {
  int tid = threadIdx.x, wave = tid >> 6, lane = tid & 63;
  int g = lane >> 4, li = lane & 15;
  int bid = blockIdx.x;
  int qt = 31 - (bid >> 5);  // big-work blocks first
  int bh = bid & 31;
  int b = bh >> 4, h = bh & 15;
  int mw = wave * 16;

  const float* Qp = Qt + (size_t)bh * 3 * T_SEQ;
  const float* Kp = Kt + (size_t)bh * 3 * T_SEQ;
  const bf16_t* Vp = VT + (size_t)bh * 64 * T_SEQ;

  int tq = qt * 64 + mw + li;  // this lane's query row (score phase)
  float q0 = Qp[tq], q1 = Qp[T_SEQ + tq], q2 = Qp[2 * T_SEQ + tq];

  bf16x8 bones;  // B[n=li][k]=1 iff li==0 -> D[:,0] = rowsum
  unsigned short ob = (li == 0) ? (unsigned short)0x3F80 : (unsigned short)0;
#pragma unroll
  for (int j = 0; j < 8; ++j) bones[j] = (short)ob;

  f32x4 acc[5] = {};

  for (int st = 0; st <= qt; ++st) {
    int s0 = st * 64;
    bool diag = (st == qt);
    bf16x8 afrag[2];
#pragma unroll
    for (int half = 0; half < 2; ++half) {
      const float* kp = Kp + s0 + half * 32 + g * 8;
      f32x4 k0a = *(const f32x4*)kp, k0b = *(const f32x4*)(kp + 4);
      f32x4 k1a = *(const f32x4*)(kp + T_SEQ), k1b = *(const f32x4*)(kp + T_SEQ + 4);
      f32x4 k2a = *(const f32x4*)(kp + 2 * T_SEQ), k2b = *(const f32x4*)(kp + 2 * T_SEQ + 4);
#pragma unroll
      for (int j = 0; j < 8; ++j) {
        float kk0 = (j < 4) ? k0a[j & 3] : k0b[j & 3];
        float kk1 = (j < 4) ? k1a[j & 3] : k1b[j & 3];
        float kk2 = (j < 4) ? k2a[j & 3] : k2b[j & 3];
        float scv = q0 * kk0 + q1 * kk1 + q2 * kk2;
        float pv = __expf(fminf(scv, 80.0f));
        if (diag && (half * 32 + g * 8 + j > mw + li)) pv = 0.0f;  // causal
        afrag[half][j] = (short)f2bf(pv);
      }
    }
#pragma unroll
    for (int nt = 0; nt < 4; ++nt) {
      const bf16_t* vrow = Vp + (size_t)(nt * 16 + li) * T_SEQ + s0 + g * 8;
      bf16x8 b0 = *(const bf16x8*)vrow;
      bf16x8 b1 = *(const bf16x8*)(vrow + 32);
      acc[nt] = mfma16(afrag[0], b0, acc[nt]);
      acc[nt] = mfma16(afrag[1], b1, acc[nt]);
    }
    acc[4] = mfma16(afrag[0], bones, acc[4]);
    acc[4] = mfma16(afrag[1], bones, acc[4]);
  }

  float linv[4];
#pragma unroll
  for (int r = 0; r < 4; ++r)
    linv[r] = 1.0f / fmaxf(__shfl(acc[4][r], lane & 48), 1e-35f);

#pragma unroll
  for (int nt = 0; nt < 4; ++nt)
#pragma unroll
    for (int r = 0; r < 4; ++r) {
      int t = qt * 64 + mw + g * 4 + r;
      att[((size_t)b * T_SEQ + t) * CDIM + h * 64 + nt * 16 + li] =
          __float2bfloat16(acc[nt][r] * linv[r]);
    }
}

// ---------------- launch ----------------
extern "C" void kernel_launch(void* const* d_in, const int* in_sizes, int n_in,
                              void* d_out, int out_size, void* d_ws, size_t ws_size,
                              hipStream_t stream) {
  const float* x  = (const float*)d_in[0];
  const float* wq = (const float*)d_in[1];
  const float* wk = (const float*)d_in[2];
  const float* wv = (const float*)d_in[3];
  const float* wo = (const float*)d_in[4];
  const float* hd = (const float*)d_in[5];
  const float* sc = (const float*)d_in[6];
  float* out = (float*)d_out;

  // workspace layout (bytes), ~31 MB total
  char* ws = (char*)d_ws;
  bf16_t* wqkT = (bf16_t*)(ws + 0);          // 96*1024*2      = 196608
  bf16_t* wvT  = (bf16_t*)(ws + 196608);     // 1024*1024*2    = 2097152
  bf16_t* woT  = (bf16_t*)(ws + 2293760);    // 1024*1024*2
  float*  Qt   = (float*)(ws + 4390912);     // 3*32*2048*4    = 786432
  float*  Kt   = (float*)(ws + 5177344);     // 786432
  bf16_t* VT   = (bf16_t*)(ws + 5963776);    // 32*64*2048*2   = 8388608
  bf16_t* att  = (bf16_t*)(ws + 14352384);   // 4096*1024*2    = 8388608
  bf16_t* xb   = (bf16_t*)(ws + 22740992);   // 4096*1024*2    = 8388608

  k_cast<<<4096, 256, 0, stream>>>((const float4*)x, (ushort4*)xb, 1048576);

  k_transpose<<<dim3(2, 32), 256, 0, stream>>>(wq, wqkT, 1024, 48);
  k_transpose<<<dim3(2, 32), 256, 0, stream>>>(wk, wqkT + 48 * 1024, 1024, 48);
  k_transpose<<<dim3(32, 32), 256, 0, stream>>>(wv, wvT, 1024, 1024);
  k_transpose<<<dim3(32, 32), 256, 0, stream>>>(wo, woT, 1024, 1024);

  k_qkproj<<<256, 256, 0, stream>>>(xb, wqkT, hd, sc, Qt, Kt);

  // VT[vdim][b,t] = sum_k wvT[vdim][k] * xb[b,t][k]
  k_gemm_bt<<<dim3(32, 16), 256, 0, stream>>>(wvT, xb, VT, 1024, 4096, 1024, 0);

  k_attn<<<1024, 256, 0, stream>>>(Qt, Kt, VT, att);

  // out = att @ wo (fp32 out)
  k_gemm_bt<<<dim3(8, 64), 256, 0, stream>>>(att, woT, out, 4096, 1024, 1024, 1);
}

// Round 5
// 180.749 us; speedup vs baseline: 1.3667x; 1.3667x over previous
//
#include <hip/hip_runtime.h>
#include <hip/hip_bf16.h>

// GeometricAttention on MI355X (gfx950).
// B=2, T=2048, C=1024, H=16, hd=64, QK-dim=3.
// d_in are float*, d_out is float*. Internally bf16 MFMA (fp32 accumulate).
// R5: k_attn = A-frag P in registers (R4) + V staged via global_load_lds with
//     XOR-chunk swizzle + double buffer (1 barrier/tile) + K register prefetch.
//     k_prep fuses cast + 4 transposes (9 -> 5 kernels).

typedef short bf16x8 __attribute__((ext_vector_type(8)));
typedef float f32x4 __attribute__((ext_vector_type(4)));
typedef __hip_bfloat16 bf16_t;
typedef unsigned int __attribute__((address_space(1))) u32_as1;
typedef unsigned int __attribute__((address_space(3))) u32_as3;

#define T_SEQ 2048
#define NHEAD 16
#define CDIM 1024

__device__ __forceinline__ void gl_lds16(const void* g, void* l) {
  __builtin_amdgcn_global_load_lds((const u32_as1*)g, (u32_as3*)l, 16, 0, 0);
}

__device__ __forceinline__ f32x4 mfma16(bf16x8 a, bf16x8 b, f32x4 c) {
  return __builtin_amdgcn_mfma_f32_16x16x32_bf16(a, b, c, 0, 0, 0);
}

__device__ __forceinline__ unsigned short f2bf(float f) {
  __hip_bfloat16 h = __float2bfloat16(f);
  return *(unsigned short*)&h;
}

// ---------------- fused prep: cast x -> xb, transpose+cast 4 weights ----------------
// blocks 0..4095: cast (4 float4/thread); 4096..5119: wv; 5120..6143: wo;
// 6144..6207: wq; 6208..6271: wk.
__global__ __launch_bounds__(256) void k_prep(const float* __restrict__ x,
                                              const float* __restrict__ wq,
                                              const float* __restrict__ wk,
                                              const float* __restrict__ wv,
                                              const float* __restrict__ wo,
                                              bf16_t* __restrict__ xb,
                                              bf16_t* __restrict__ wqkT,
                                              bf16_t* __restrict__ wvT,
                                              bf16_t* __restrict__ woT) {
  __shared__ bf16_t tile[32][33];
  int bid = blockIdx.x, tid = threadIdx.x;
  if (bid < 4096) {
    int i = bid * 256 + tid;
    float4 v = ((const float4*)x)[i];
    ushort4 o;
    o.x = f2bf(v.x); o.y = f2bf(v.y); o.z = f2bf(v.z); o.w = f2bf(v.w);
    ((ushort4*)xb)[i] = o;
    return;
  }
  const float* src; bf16_t* dst; int R, C, bx, by;
  if (bid < 5120)      { int t = bid - 4096; src = wv; dst = wvT;            R = 1024; C = 1024; bx = t & 31; by = t >> 5; }
  else if (bid < 6144) { int t = bid - 5120; src = wo; dst = woT;            R = 1024; C = 1024; bx = t & 31; by = t >> 5; }
  else if (bid < 6208) { int t = bid - 6144; src = wq; dst = wqkT;           R = 1024; C = 48;   bx = t & 1;  by = t >> 1; }
  else                 { int t = bid - 6208; src = wk; dst = wqkT + 48*1024; R = 1024; C = 48;   bx = t & 1;  by = t >> 1; }
  int tx = tid & 31, ty = tid >> 5;
  int r0 = by * 32, c0 = bx * 32;
#pragma unroll
  for (int j = 0; j < 32; j += 8) {
    int r = r0 + ty + j, c = c0 + tx;
    if (r < R && c < C) tile[ty + j][tx] = __float2bfloat16(src[(size_t)r * C + c]);
  }
  __syncthreads();
#pragma unroll
  for (int j = 0; j < 32; j += 8) {
    int c = c0 + ty + j, r = r0 + tx;
    if (r < R && c < C) dst[(size_t)c * R + r] = tile[tx][ty + j];
  }
}

// ---------------- QK projection (M=4096, N=96, K=1024), split-K x4 ----------------
__global__ __launch_bounds__(256) void k_qkproj(const bf16_t* __restrict__ xb,
                                                const bf16_t* __restrict__ wqkT,
                                                const float* __restrict__ head_dirs,
                                                const float* __restrict__ scale,
                                                float* __restrict__ Qt,
                                                float* __restrict__ Kt) {
  __shared__ float red[4][16][96];  // 24 KB
  int tid = threadIdx.x, wave = tid >> 6, lane = tid & 63;
  int g = lane >> 4, li = lane & 15;
  int m0 = blockIdx.x * 16;
  f32x4 acc[6] = {};
  int kb = wave * 256;
  for (int k0 = kb; k0 < kb + 256; k0 += 32) {
    bf16x8 a = *(const bf16x8*)(xb + (size_t)(m0 + li) * 1024 + k0 + g * 8);
#pragma unroll
    for (int nt = 0; nt < 6; ++nt) {
      bf16x8 bb = *(const bf16x8*)(wqkT + (size_t)(nt * 16 + li) * 1024 + k0 + g * 8);
      acc[nt] = mfma16(a, bb, acc[nt]);
    }
  }
#pragma unroll
  for (int nt = 0; nt < 6; ++nt)
#pragma unroll
    for (int r = 0; r < 4; ++r) red[wave][g * 4 + r][nt * 16 + li] = acc[nt][r];
  __syncthreads();
  for (int i = tid; i < 16 * 96; i += 256) {
    int row = i / 96, col = i - (i / 96) * 96;
    float v = red[0][row][col] + red[1][row][col] + red[2][row][col] + red[3][row][col];
    if (col >= 48) {
      int n = col - 48;
      int h = n / 3, c = n - h * 3;
      int mg = m0 + row;
      int bb = mg >> 11, tt = mg & 2047;
      Kt[(((size_t)bb * NHEAD + h) * 3 + c) * T_SEQ + tt] = v;
    } else {
      red[0][row][col] = v;
    }
  }
  __syncthreads();
  int row = tid >> 4, h = tid & 15;
  float q0 = red[0][row][h * 3 + 0];
  float q1 = red[0][row][h * 3 + 1];
  float q2 = red[0][row][h * 3 + 2];
  float d0 = head_dirs[h * 3 + 0];
  float d1 = head_dirs[h * 3 + 1];
  float d2 = head_dirs[h * 3 + 2];
  float sc = scale[0];
  float dot = q0 * d0 + q1 * d1 + q2 * d2;
  int mg = m0 + row;
  int bb = mg >> 11, tt = mg & 2047;
  size_t base = ((size_t)bb * NHEAD + h) * 3 * T_SEQ + tt;
  Qt[base] = sc * q0 + d0 * dot;
  Qt[base + T_SEQ] = sc * q1 + d1 * dot;
  Qt[base + 2 * T_SEQ] = sc * q2 + d2 * dot;
}

// ---------------- 64x128x32 MFMA GEMM, B^T input ----------------
__global__ __launch_bounds__(256) void k_gemm_bt(const bf16_t* __restrict__ A,
                                                 const bf16_t* __restrict__ Bt,
                                                 void* __restrict__ Cout,
                                                 int M, int N, int K, int mode) {
  __shared__ alignas(16) bf16_t As[64 * 32];
  __shared__ alignas(16) bf16_t Bs[128 * 32];
  int tid = threadIdx.x, wave = tid >> 6, lane = tid & 63;
  int g = lane >> 4, li = lane & 15;
  int n0 = blockIdx.x * 128, m0 = blockIdx.y * 64;
  int wm = wave >> 1, wn = wave & 1;

  const bf16_t* gA0 = A + (size_t)(m0 + (tid >> 2)) * K + (tid & 3) * 8;
  const bf16_t* gB0 = Bt + (size_t)(n0 + (tid >> 2)) * K + (tid & 3) * 8;
  const bf16_t* gB1 = Bt + (size_t)(n0 + 64 + (tid >> 2)) * K + (tid & 3) * 8;
  char* lA = (char*)As + (size_t)(wave * 64) * 16;
  char* lB0 = (char*)Bs + (size_t)(wave * 64) * 16;
  char* lB1 = (char*)Bs + (size_t)(256 + wave * 64) * 16;

  f32x4 acc[2][4] = {};

  for (int k0 = 0; k0 < K; k0 += 32) {
    __syncthreads();
    gl_lds16(gA0 + k0, lA);
    gl_lds16(gB0 + k0, lB0);
    gl_lds16(gB1 + k0, lB1);
    __syncthreads();
    bf16x8 af[2], bfr[4];
#pragma unroll
    for (int mt = 0; mt < 2; ++mt)
      af[mt] = *(const bf16x8*)&As[(wm * 32 + mt * 16 + li) * 32 + g * 8];
#pragma unroll
    for (int nt = 0; nt < 4; ++nt)
      bfr[nt] = *(const bf16x8*)&Bs[(wn * 64 + nt * 16 + li) * 32 + g * 8];
#pragma unroll
    for (int mt = 0; mt < 2; ++mt)
#pragma unroll
      for (int nt = 0; nt < 4; ++nt)
        acc[mt][nt] = mfma16(af[mt], bfr[nt], acc[mt][nt]);
  }

#pragma unroll
  for (int mt = 0; mt < 2; ++mt)
#pragma unroll
    for (int nt = 0; nt < 4; ++nt)
#pragma unroll
      for (int r = 0; r < 4; ++r) {
        int m = m0 + wm * 32 + mt * 16 + g * 4 + r;
        int n = n0 + wn * 64 + nt * 16 + li;
        float v = acc[mt][nt][r];
        if (mode == 0) {
          int bb = n >> 11, tt = n & 2047;
          ((bf16_t*)Cout)[((size_t)bb * 1024 + m) * T_SEQ + tt] = __float2bfloat16(v);
        } else {
          ((float*)Cout)[(size_t)m * N + n] = v;
        }
      }
}

// ---------------- attention ----------------
// block = 256 thr (4 waves), one (b,h) x 64-query tile; wave = 16 queries.
// P built in A-frag registers (lane li = query, k-slot g*8+j = key).
// V staged global->LDS async (XOR-swizzled 16B chunks), double-buffered,
// 1 barrier/tile. K prefetched into registers 1 tile ahead.
// Rowsums via ones B-frag (D[:,0]).
__global__ __launch_bounds__(256) void k_attn(const float* __restrict__ Qt,
                                              const float* __restrict__ Kt,
                                              const bf16_t* __restrict__ VT,
                                              bf16_t* __restrict__ att) {
  __shared__ alignas(16) bf16_t Vb[2][64 * 64];  // 16 KB, swizzled
  int tid = threadIdx.x, wave = tid >> 6, lane = tid & 63;
  int g = lane >> 4, li = lane & 15;
  int bid = blockIdx.x;
  int qt = 31 - (bid >> 5);  // big-work blocks first
  int bh = bid & 31;
  int b = bh >> 4, h = bh & 15;
  int mw = wave * 16;

  const float* Qp = Qt + (size_t)bh * 3 * T_SEQ;
  const float* Kp = Kt + (size_t)bh * 3 * T_SEQ;
  const bf16_t* Vp = VT + (size_t)bh * 64 * T_SEQ;

  int tq = qt * 64 + mw + li;
  float q0 = Qp[tq], q1 = Qp[T_SEQ + tq], q2 = Qp[2 * T_SEQ + tq];

  bf16x8 bones;  // B[n=li][k]=1 iff li==0 -> D[:,0] = rowsum
  unsigned short ob = (li == 0) ? (unsigned short)0x3F80 : (unsigned short)0;
#pragma unroll
  for (int j = 0; j < 8; ++j) bones[j] = (short)ob;

  // per-thread global V chunk pointers (chunk swizzle on the global side):
  // phys chunk P = p*256 + wave*64 + lane -> row d=P>>3, phys c=P&7,
  // logical chunk = (P&7) ^ (d&7); global addr = row d, chunk logical.
  const bf16_t* vg[2];
#pragma unroll
  for (int p = 0; p < 2; ++p) {
    int P = p * 256 + wave * 64 + lane;
    int d = P >> 3, c = (P & 7) ^ (d & 7);
    vg[p] = Vp + (size_t)d * T_SEQ + c * 8;
  }
  char* vl0[2] = {(char*)&Vb[0][0] + wave * 64 * 16, (char*)&Vb[1][0] + wave * 64 * 16};
  char* vl1[2] = {(char*)&Vb[0][0] + (256 + wave * 64) * 16,
                  (char*)&Vb[1][0] + (256 + wave * 64) * 16};

  f32x4 kreg[2][3][2];
#define LOAD_K(s0)                                                        \
  {                                                                       \
    _Pragma("unroll") for (int half = 0; half < 2; ++half) {              \
      const float* kp = Kp + (s0) + half * 32 + g * 8;                    \
      _Pragma("unroll") for (int c = 0; c < 3; ++c) {                     \
        kreg[half][c][0] = *(const f32x4*)(kp + c * T_SEQ);               \
        kreg[half][c][1] = *(const f32x4*)(kp + c * T_SEQ + 4);           \
      }                                                                   \
    }                                                                     \
  }

  LOAD_K(0);
  gl_lds16(vg[0], vl0[0]);
  gl_lds16(vg[1], vl1[0]);

  f32x4 acc[5] = {};
  int sw = li & 7;

  for (int st = 0; st <= qt; ++st) {
    int buf = st & 1;
    __syncthreads();  // drains vmcnt (tile st ready) + frees buf^1
    if (st < qt) {
      int s1 = (st + 1) * 64;
      gl_lds16(vg[0] + s1, vl0[buf ^ 1]);
      gl_lds16(vg[1] + s1, vl1[buf ^ 1]);
    }
    // scores -> A-frag (P) from kreg
    bf16x8 afrag[2];
    bool diag = (st == qt);
#pragma unroll
    for (int half = 0; half < 2; ++half)
#pragma unroll
      for (int j = 0; j < 8; ++j) {
        float kk0 = kreg[half][0][j >> 2][j & 3];
        float kk1 = kreg[half][1][j >> 2][j & 3];
        float kk2 = kreg[half][2][j >> 2][j & 3];
        float scv = q0 * kk0 + q1 * kk1 + q2 * kk2;
        float pv = __expf(fminf(scv, 80.0f));
        if (diag && (half * 32 + g * 8 + j > mw + li)) pv = 0.0f;  // causal
        afrag[half][j] = (short)f2bf(pv);
      }
    if (st < qt) LOAD_K((st + 1) * 64);  // prefetch K under MFMA below
    const bf16_t* vb = &Vb[buf][0];
#pragma unroll
    for (int nt = 0; nt < 4; ++nt) {
      int row = nt * 16 + li;
      bf16x8 b0 = *(const bf16x8*)&vb[row * 64 + (g ^ sw) * 8];
      bf16x8 b1 = *(const bf16x8*)&vb[row * 64 + ((4 + g) ^ sw) * 8];
      acc[nt] = mfma16(afrag[0], b0, acc[nt]);
      acc[nt] = mfma16(afrag[1], b1, acc[nt]);
    }
    acc[4] = mfma16(afrag[0], bones, acc[4]);
    acc[4] = mfma16(afrag[1], bones, acc[4]);
  }

  float linv[4];
#pragma unroll
  for (int r = 0; r < 4; ++r)
    linv[r] = 1.0f / fmaxf(__shfl(acc[4][r], lane & 48), 1e-35f);

#pragma unroll
  for (int nt = 0; nt < 4; ++nt)
#pragma unroll
    for (int r = 0; r < 4; ++r) {
      int t = qt * 64 + mw + g * 4 + r;
      att[((size_t)b * T_SEQ + t) * CDIM + h * 64 + nt * 16 + li] =
          __float2bfloat16(acc[nt][r] * linv[r]);
    }
}

// ---------------- launch ----------------
extern "C" void kernel_launch(void* const* d_in, const int* in_sizes, int n_in,
                              void* d_out, int out_size, void* d_ws, size_t ws_size,
                              hipStream_t stream) {
  const float* x  = (const float*)d_in[0];
  const float* wq = (const float*)d_in[1];
  const float* wk = (const float*)d_in[2];
  const float* wv = (const float*)d_in[3];
  const float* wo = (const float*)d_in[4];
  const float* hd = (const float*)d_in[5];
  const float* sc = (const float*)d_in[6];
  float* out = (float*)d_out;

  char* ws = (char*)d_ws;
  bf16_t* wqkT = (bf16_t*)(ws + 0);          // 96*1024*2      = 196608
  bf16_t* wvT  = (bf16_t*)(ws + 196608);     // 1024*1024*2    = 2097152
  bf16_t* woT  = (bf16_t*)(ws + 2293760);    // 1024*1024*2
  float*  Qt   = (float*)(ws + 4390912);     // 3*32*2048*4    = 786432
  float*  Kt   = (float*)(ws + 5177344);     // 786432
  bf16_t* VT   = (bf16_t*)(ws + 5963776);    // 32*64*2048*2   = 8388608
  bf16_t* att  = (bf16_t*)(ws + 14352384);   // 4096*1024*2    = 8388608
  bf16_t* xb   = (bf16_t*)(ws + 22740992);   // 4096*1024*2    = 8388608

  k_prep<<<6272, 256, 0, stream>>>(x, wq, wk, wv, wo, xb, wqkT, wvT, woT);

  k_qkproj<<<256, 256, 0, stream>>>(xb, wqkT, hd, sc, Qt, Kt);

  // VT[vdim][b,t] = sum_k wvT[vdim][k] * xb[b,t][k]
  k_gemm_bt<<<dim3(32, 16), 256, 0, stream>>>(wvT, xb, VT, 1024, 4096, 1024, 0);

  k_attn<<<1024, 256, 0, stream>>>(Qt, Kt, VT, att);

  // out = att @ wo (fp32 out)
  k_gemm_bt<<<dim3(8, 64), 256, 0, stream>>>(att, woT, out, 4096, 1024, 1024, 1);
}